// Round 8
// baseline (545.984 us; speedup 1.0000x reference)
//
#include <hip/hip_runtime.h>

// ResNetBlock_MoE: B=64,C=64,H=W=56,E=8,TOPK=2. f32 in / f32 out.
// out = sum_k w_k*relu(bn2(conv2(relu(bn1(conv1(x,e)))))+x), plus dense_w.
//
// R19: R18 (241.6us, convs ~83us each) still 58% stalled (Mfma 15.7 + VALU 26).
// Two fixes:
//  1. Zero-page offset tables: per-tap/per-frag u32 byte offsets precomputed
//     once (valid -> p*32+h*16, invalid -> zero tail appended to g_xb/g_h).
//     Refill = 1 v_add + saddr global_load_dwordx4 (was ~12 VALU clamp/cndmask
//     chain) -> loads issue earlier, VALU clears. Valid taps never need the
//     pc clamp (y/xc checks imply p in range); tail tiles (gn>=3136) fail the
//     y-check on all taps -> all-zero B -> epilogue skip unchanged.
//  2. Launch fusion: pack+xconv+gate -> one prep kernel; gate runs in the
//     last xconv block per b (atomic pool + ticket, self-resetting across
//     bench iterations). 5 launches -> 3 (~60us of inter-kernel gap at R18).
// Keeps: kq-plane activations (R18's 4x L2-line fix), barrier-free 36-step
// loop, conflict-free A LDS, XCD-chunked swizzle, A-reg pipeline depth 3,
// B depth 6, conv2 LDS combine, capture-before-refill.

#define BATCH 64
#define CH    64
#define HW_   3136            // 56*56
#define IMG_  (CH*HW_)        // 200704
#define PLANE (HW_*16)        // 50176 u16: one kq-plane [pos][ch16]
#define NE    8
#define JOBS  128
#define PWSZ  36864           // per-expert packed weights: 36*2mt*2h*32m*8j (u16)
#define NTILE 13              // ceil(3136/256) position tiles
#define BD    6               // B-prefetch depth in steps (x2 frags = 12 loads)
#define CGRID (NTILE*2*BATCH) // 1664 = 8 XCDs * 208

typedef unsigned short u16;
typedef __attribute__((ext_vector_type(8))) short short8_t;   // 8 bf16 = 4 VGPR
typedef __attribute__((ext_vector_type(16))) float floatx16;  // 32x32 MFMA acc

// +4*PLANE zero tails (never written; .bss zero-init) back the invalid-tap
// offsets: any off in [zoff, zoff+3*PLANE*2+16] reads zeros.
__device__ u16   g_xb[(size_t)BATCH*IMG_ + 4*PLANE];  // x bf16 [b][kq][pos][ch16]
__device__ u16   g_h[(size_t)JOBS*IMG_ + 4*PLANE];    // conv1 out [job][kq][pos][ch16]
__device__ u16   g_pw1[NE * PWSZ];            // packed conv1 w (bn1_s folded)
__device__ u16   g_pw2[NE * PWSZ];            // packed conv2 w (bn2_s folded)
__device__ int   g_eid[JOBS];
__device__ float g_wgt[JOBS];
__device__ float g_pool[BATCH * CH];          // GAP atomic accum (winner-reset)
__device__ unsigned g_tick[BATCH];            // per-b ticket (winner-reset)

__device__ __forceinline__ u16 f2b(float f) {
    unsigned v; __builtin_memcpy(&v, &f, 4);
    return (u16)((v + 0x7FFFu + ((v >> 16) & 1u)) >> 16);   // RNE
}

// ---------------- fused prep: pack + xconv(+GAP) + gate ---------------------
// grid = 2304 (pack) + 3136 (xconv) blocks of 256.
// pack: packed[e][s36][mt][h][m][j] = w[e][M][ci][tap]*bn_s[e][M],
//   s36 = tap*4+kq, ci = kq*16+h*8+j, M = mt*32+m.
// xconv: x NCHW f32 -> g_xb [kq][pos][ch16] bf16, GAP via atomicAdd; the
//   49th-finishing block per b computes the gate (top-2 softmax) inline.
__global__ __launch_bounds__(256) void prep_kernel(
    const float* __restrict__ x,
    const float* __restrict__ w1, const float* __restrict__ s1,
    const float* __restrict__ w2, const float* __restrict__ s2,
    const float* __restrict__ gw, const float* __restrict__ gb,
    float* __restrict__ dw_out)
{
    int bid = blockIdx.x;
    int tid = threadIdx.x;
    if (bid < 2304) {                       // ---- pack (whole block) ----
        int idx = bid * 256 + tid;          // < 589824
        int conv = idx / 294912;
        int i2 = idx - conv * 294912;
        int e = i2 / PWSZ;   int r = i2 - e * PWSZ;
        int s36 = r >> 10;   int r2 = r & 1023;
        int mt  = r2 >> 9;   int r3 = r2 & 511;
        int h   = r3 >> 8;   int r4 = r3 & 255;
        int m   = r4 >> 3;   int j  = r4 & 7;
        int tap = s36 >> 2;
        int ci  = ((s36 & 3) << 4) | (h << 3) | j;
        int M   = mt*32 + m;
        const float* w  = conv ? w2 : w1;
        const float* sc = conv ? s2 : s1;
        float v = w[((e*64 + M)*64 + ci)*9 + tap] * sc[e*64 + M];
        (conv ? g_pw2 : g_pw1)[i2] = f2b(v);
        return;
    }
    // ---- xconv ----
    __shared__ u16 T[64*66];                // [pos][ch], stride 66
    __shared__ float pooled[CH];
    __shared__ float logits[NE];
    __shared__ int last;
    int xid = bid - 2304;
    int b = xid / 49;
    int tile = xid - b*49;
    int pos0 = tile * 64;
    int pin = tid & 63;
    int c0 = tid >> 6;                      // 0..3
    const float* xb = x + (size_t)b*IMG_ + pos0 + pin;
    #pragma unroll
    for (int i = 0; i < 16; i++) {
        int ch = c0*16 + i;
        T[pin*66 + ch] = f2b(xb[ch*HW_]);   // coalesced 256B f32 read per instr
    }
    __syncthreads();
    u16* ob = g_xb + (size_t)b*IMG_ + (size_t)pos0*16;   // within-plane offset
    #pragma unroll
    for (int i = 0; i < 16; i++) {
        int j = tid + i*256;                // 0..4095
        int kq  = j >> 10;
        int pos = (j >> 4) & 63;
        int c16 = j & 15;
        ob[(size_t)kq*PLANE + pos*16 + c16] = T[pos*66 + kq*16 + c16];
    }
    // GAP partial: threads 0..63 sum their channel over the 64 positions.
    if (tid < 64) {
        float s = 0.f;
        const float* xc = x + (size_t)b*IMG_ + tid*HW_ + pos0;
        #pragma unroll 4
        for (int p = 0; p < 64; p++) s += xc[p];
        atomicAdd(&g_pool[b*64 + tid], s);
    }
    __syncthreads();                        // pool adds drained (vmcnt0)
    __threadfence();
    if (tid == 0) {
        unsigned o = atomicAdd(&g_tick[b], 1u);
        last = (o == 48);
        if (o == 48) g_tick[b] = 0;         // self-reset for next bench iter
    }
    __syncthreads();
    if (!last) return;
    // ---- gate for this b (winner block; all 256 threads hit barriers) ----
    if (tid < 64) {
        float v = atomicExch(&g_pool[b*64 + tid], 0.f);   // read + reset
        pooled[tid] = v * (1.f/3136.f);
    }
    __syncthreads();
    if (tid < NE) {
        float l = gb[tid];
        for (int c = 0; c < CH; c++) l += pooled[c] * gw[tid*CH + c];
        logits[tid] = l;
    }
    __syncthreads();
    if (tid == 0) {
        int i1 = 0; float v1 = logits[0];
        for (int e = 1; e < NE; e++) if (logits[e] > v1) { v1 = logits[e]; i1 = e; }
        int i2 = -1; float v2 = -3.4e38f;
        for (int e = 0; e < NE; e++) if (e != i1 && logits[e] > v2) { v2 = logits[e]; i2 = e; }
        float eb = __expf(v2 - v1);
        float wa = 1.f / (1.f + eb), wb = eb / (1.f + eb);
        for (int e = 0; e < NE; e++) dw_out[b*NE + e] = 0.f;
        dw_out[b*NE + i1] = wa;
        dw_out[b*NE + i2] = wb;
        g_eid[2*b] = i1; g_eid[2*b+1] = i2;
        g_wgt[2*b] = wa; g_wgt[2*b+1] = wb;
    }
}

// Single-shot A stage: both experts' mt-slice, 72KB = 4608 16B-units,
// 9 rounds of 512 threads. AL layout: [s36][es][h][m32][j8].
__device__ __forceinline__ void stageA(
    u16* AL, const u16* __restrict__ pw0, const u16* __restrict__ pw1,
    int mt, int tid)
{
    short8_t st[9];
    #pragma unroll
    for (int i = 0; i < 9; i++) {
        int u = i*512 + tid;
        int es = u >= 2304;
        int r = u - (es ? 2304 : 0);
        int s36 = r >> 6;
        int c = r & 63;
        st[i] = *(const short8_t*)((es ? pw1 : pw0) + s36*1024 + mt*512 + c*8);
    }
    #pragma unroll
    for (int i = 0; i < 9; i++) {
        int u = i*512 + tid;
        int es = u >= 2304;
        int r = u - (es ? 2304 : 0);
        int s36 = r >> 6;
        int c = r & 63;
        *(short8_t*)(AL + (s36*2 + es)*512 + c*8) = st[i];
    }
}

// Per-tap offset tables: valid -> p*32 + h*16 bytes within the base image;
// invalid -> zoff (zero tail). kq adds a compile-time plane-stride constant.
__device__ __forceinline__ void mkOffs(
    unsigned* off, int gn, int y, int xc, int h, unsigned zoff)
{
    #pragma unroll
    for (int tap = 0; tap < 9; tap++) {
        int dy = tap/3 - 1, dx = tap - (tap/3)*3 - 1;
        int p = gn + dy*56 + dx;
        bool vld = ((unsigned)(y + dy) < 56u) && ((unsigned)(xc + dx) < 56u);
        off[tap] = vld ? (unsigned)(p*32 + h*16) : zoff;
    }
}
#define LOADB(base, off, kq) (*(const short8_t*)((base) + (off) + (unsigned)((kq)*PLANE*2)))

// ---------------- conv1 + bn1 + relu -> g_h ---------------------------------
// 1D grid 1664, XCD-chunked decode: L = (wg&7)*208 + wg/8; b = L/26,
// tile = (L%26)>>1, mt = L&1 -> (tile,mt) pairs adjacent on one XCD.
__global__ __launch_bounds__(512, 4) void conv1_kernel(const float* __restrict__ b1)
{
    __shared__ u16 AL[36864];           // 72KB, staged once
    int wg = blockIdx.x;
    int L  = (wg & 7) * (CGRID/8) + (wg >> 3);
    int b  = L / 26;
    int r  = L - b*26;
    int tile = r >> 1;
    int mt   = r & 1;
    int e0 = g_eid[2*b], e1 = g_eid[2*b+1];
    int tid = threadIdx.x;
    int lane = tid & 63, w = tid >> 6;  // 8 waves
    int es = w & 1, pg = w >> 1;        // expert slot (2), position group (4)
    int l31 = lane & 31, h = lane >> 5;
    int gn0 = tile*256 + pg*64 + l31;   // frag 0 position (may be >= 3136)
    int gn1 = gn0 + 32;                 // frag 1 position
    int y0 = gn0/56, xc0 = gn0 - y0*56;
    int y1 = gn1/56, xc1 = gn1 - y1*56;
    int e = es ? e1 : e0;
    const char* base = (const char*)(g_xb + (size_t)b*IMG_);
    unsigned zoff = (unsigned)((size_t)(BATCH - b)*IMG_*2);
    const u16* pw0 = g_pw1 + e0*PWSZ;
    const u16* pw1 = g_pw1 + e1*PWSZ;
    int aOff = es*512 + h*256 + l31*8;  // + s*1024

    unsigned off0[9], off1[9];
    mkOffs(off0, gn0, y0, xc0, h, zoff);
    mkOffs(off1, gn1, y1, xc1, h, zoff);

    floatx16 accA = {}, accB = {};      // frag 0 / frag 1 accumulators
    short8_t B0[BD], B1[BD];
    #pragma unroll
    for (int s = 0; s < BD; s++) {      // B prefetch issues FIRST (longest latency)
        B0[s] = LOADB(base, off0[s >> 2], s & 3);
        B1[s] = LOADB(base, off1[s >> 2], s & 3);
    }
    stageA(AL, pw0, pw1, mt, tid);
    __syncthreads();                    // the ONLY barrier

    short8_t Ar[3];                     // A register pipeline, depth 3
    #pragma unroll
    for (int i = 0; i < 3; i++)
        Ar[i] = *(const short8_t*)(AL + i*1024 + aOff);

    #pragma unroll
    for (int s = 0; s < 36; s++) {
        short8_t bb0 = B0[s % BD];      // capture BEFORE refill
        short8_t bb1 = B1[s % BD];
        int sp = s + BD;
        if (sp < 36) {                  // refill: 1 add + saddr load each
            B0[s % BD] = LOADB(base, off0[sp >> 2], sp & 3);
            B1[s % BD] = LOADB(base, off1[sp >> 2], sp & 3);
        }
        short8_t a = Ar[s % 3];
        if (s + 3 < 36)                 // A refill 3 steps ahead (lgkmcnt cover)
            Ar[s % 3] = *(const short8_t*)(AL + (s+3)*1024 + aOff);
        accA = __builtin_amdgcn_mfma_f32_32x32x16_bf16(a, bb0, accA, 0, 0, 0);
        accB = __builtin_amdgcn_mfma_f32_32x32x16_bf16(a, bb1, accB, 0, 0, 0);
    }

    // epilogue -> g_h [kq][pos][ch16]: kq = mt*2 + (rg>>1), c = (rg&1)*8 + h*4
    u16* hb = g_h + (size_t)(2*b + es)*IMG_;
    #pragma unroll
    for (int f = 0; f < 2; f++) {
        int gn = f ? gn1 : gn0;
        if (gn < HW_) {
            #pragma unroll
            for (int rg = 0; rg < 4; rg++) {
                union { u16 u[4]; uint2 v; } t;
                #pragma unroll
                for (int rr = 0; rr < 4; rr++) {
                    int m = rg*8 + h*4 + rr;       // D row = (reg&3)+8*(reg>>2)+4*h
                    float v = (f ? accB : accA)[rg*4 + rr] + b1[e*64 + mt*32 + m];
                    t.u[rr] = f2b(fmaxf(v, 0.f));
                }
                int kq = mt*2 + (rg >> 1);
                *(uint2*)(hb + (size_t)kq*PLANE + (size_t)gn*16 + (rg & 1)*8 + h*4) = t.v;
            }
        }
    }
}

// ---------------- conv2 + bn2 + residual + cross-wave combine ---------------
__global__ __launch_bounds__(512, 4) void conv2_kernel(
    const float* __restrict__ x, const float* __restrict__ b2,
    float* __restrict__ out)
{
    __shared__ u16 AL[36864];           // 72KB; reused as 32KB f32 P after loop
    int wg = blockIdx.x;
    int L  = (wg & 7) * (CGRID/8) + (wg >> 3);
    int b  = L / 26;                    // SAME b->XCD map as conv1 (h L2 reuse)
    int r  = L - b*26;
    int tile = (NTILE-1) - (r >> 1);    // tile-LIFO within b (newest h first)
    int mt   = r & 1;
    int e0 = g_eid[2*b], e1 = g_eid[2*b+1];
    int tid = threadIdx.x;
    int lane = tid & 63, w = tid >> 6;
    int es = w & 1, pg = w >> 1;
    int l31 = lane & 31, h = lane >> 5;
    int gn0 = tile*256 + pg*64 + l31;
    int gn1 = gn0 + 32;
    int y0 = gn0/56, xc0 = gn0 - y0*56;
    int y1 = gn1/56, xc1 = gn1 - y1*56;
    int e = es ? e1 : e0;
    float wgt = g_wgt[2*b + es];
    const char* base = (const char*)(g_h + (size_t)(2*b + es)*IMG_);
    unsigned zoff = (unsigned)((size_t)(JOBS - (2*b + es))*IMG_*2);
    const u16* pw0 = g_pw2 + e0*PWSZ;
    const u16* pw1 = g_pw2 + e1*PWSZ;
    int aOff = es*512 + h*256 + l31*8;

    unsigned off0[9], off1[9];
    mkOffs(off0, gn0, y0, xc0, h, zoff);
    mkOffs(off1, gn1, y1, xc1, h, zoff);

    floatx16 accA = {}, accB = {};
    short8_t B0[BD], B1[BD];
    #pragma unroll
    for (int s = 0; s < BD; s++) {
        B0[s] = LOADB(base, off0[s >> 2], s & 3);
        B1[s] = LOADB(base, off1[s >> 2], s & 3);
    }
    stageA(AL, pw0, pw1, mt, tid);
    __syncthreads();

    short8_t Ar[3];
    #pragma unroll
    for (int i = 0; i < 3; i++)
        Ar[i] = *(const short8_t*)(AL + i*1024 + aOff);

    #pragma unroll
    for (int s = 0; s < 36; s++) {
        short8_t bb0 = B0[s % BD];      // capture BEFORE refill
        short8_t bb1 = B1[s % BD];
        int sp = s + BD;
        if (sp < 36) {
            B0[s % BD] = LOADB(base, off0[sp >> 2], sp & 3);
            B1[s % BD] = LOADB(base, off1[sp >> 2], sp & 3);
        }
        short8_t a = Ar[s % 3];
        if (s + 3 < 36)
            Ar[s % 3] = *(const short8_t*)(AL + (s+3)*1024 + aOff);
        accA = __builtin_amdgcn_mfma_f32_32x32x16_bf16(a, bb0, accA, 0, 0, 0);
        accB = __builtin_amdgcn_mfma_f32_32x32x16_bf16(a, bb1, accB, 0, 0, 0);
    }

    // combine: es0 waves drop w0*relu(y0+x) into LDS, es1 waves add+store.
    __syncthreads();                    // all waves done reading AL
    float* P = (float*)AL;              // [pg][f][m32][l31] f32 = 32KB
    const float* xb = x + (size_t)b*IMG_ + (size_t)(mt*32)*HW_;
    if (es == 0) {
        #pragma unroll
        for (int f = 0; f < 2; f++) {
            int gn = f ? gn1 : gn0;
            if (gn < HW_) {
                #pragma unroll
                for (int rg = 0; rg < 4; rg++)
                    #pragma unroll
                    for (int rr = 0; rr < 4; rr++) {
                        int m = rg*8 + h*4 + rr;
                        float v = (f ? accB : accA)[rg*4 + rr] + b2[e*64 + mt*32 + m]
                                  + xb[(size_t)m*HW_ + gn];
                        P[((pg*2 + f)*32 + m)*32 + l31] = wgt * fmaxf(v, 0.f);
                    }
            }
        }
    }
    __syncthreads();
    if (es == 1) {
        float* ob = out + (size_t)b*IMG_ + (size_t)(mt*32)*HW_;
        #pragma unroll
        for (int f = 0; f < 2; f++) {
            int gn = f ? gn1 : gn0;
            if (gn < HW_) {
                #pragma unroll
                for (int rg = 0; rg < 4; rg++)
                    #pragma unroll
                    for (int rr = 0; rr < 4; rr++) {
                        int m = rg*8 + h*4 + rr;
                        float v = (f ? accB : accA)[rg*4 + rr] + b2[e*64 + mt*32 + m]
                                  + xb[(size_t)m*HW_ + gn];
                        ob[(size_t)m*HW_ + gn] = wgt * fmaxf(v, 0.f)
                                                 + P[((pg*2 + f)*32 + m)*32 + l31];
                    }
            }
        }
    }
}

extern "C" void kernel_launch(void* const* d_in, const int* in_sizes, int n_in,
                              void* d_out, int out_size, void* d_ws, size_t ws_size,
                              hipStream_t stream) {
    const float* x   = (const float*)d_in[0];
    const float* gw  = (const float*)d_in[1];
    const float* gb  = (const float*)d_in[2];
    const float* w1  = (const float*)d_in[3];
    const float* s1  = (const float*)d_in[4];
    const float* b1  = (const float*)d_in[5];
    const float* w2  = (const float*)d_in[6];
    const float* s2  = (const float*)d_in[7];
    const float* b2  = (const float*)d_in[8];
    float* out = (float*)d_out;
    float* dw  = out + (size_t)BATCH * IMG_;   // dense_w region of d_out (f32)

    (void)d_ws; (void)ws_size;                 // zero d_ws usage (R1/R2 aborts)

    hipLaunchKernelGGL(prep_kernel, dim3(2304 + 3136), dim3(256), 0, stream,
                       x, w1, s1, w2, s2, gw, gb, dw);
    hipLaunchKernelGGL(conv1_kernel, dim3(CGRID), dim3(512), 0, stream, b1);
    hipLaunchKernelGGL(conv2_kernel, dim3(CGRID), dim3(512), 0, stream, x, b2, out);
}

// Round 9
// 243.463 us; speedup vs baseline: 2.2426x; 2.2426x over previous
//
#include <hip/hip_runtime.h>

// ResNetBlock_MoE: B=64,C=64,H=W=56,E=8,TOPK=2. f32 in / f32 out.
// out = sum_k w_k*relu(bn2(conv2(relu(bn1(conv1(x,e)))))+x), plus dense_w.
//
// R20: R19 post-mortem — fused gate's __threadfence (device-scope fence =>
// L2 writeback on non-coherent XCD L2s) x 3136 blocks serialized the fabric:
// prep 356us with ALL pipes idle (Occ 69%, VALU 1%, HBM 2%). Revert the
// gate fusion: xconv back to per-tile partials (no atomics/fence), tiny
// gate_fin kernel sums 49. pack+xconv stay fused (independent outputs,
// no sync needed) -> 4 launches.
// Kept from R19 (now actually measurable): zero-page offset tables — B
// refill = 1 v_add + saddr global_load_dwordx4 (was ~12-op clamp/cndmask
// chain); invalid taps point at zero tails appended to g_xb/g_h.
// Keeps: kq-plane activations (R18's 4x L2-line fix), barrier-free 36-step
// loop, conflict-free A LDS, XCD-chunked swizzle, A-reg pipeline depth 3,
// B depth 6, conv2 LDS combine, capture-before-refill.

#define BATCH 64
#define CH    64
#define HW_   3136            // 56*56
#define IMG_  (CH*HW_)        // 200704
#define PLANE (HW_*16)        // 50176 u16: one kq-plane [pos][ch16]
#define NE    8
#define JOBS  128
#define PWSZ  36864           // per-expert packed weights: 36*2mt*2h*32m*8j (u16)
#define NTILE 13              // ceil(3136/256) position tiles
#define BD    6               // B-prefetch depth in steps (x2 frags = 12 loads)
#define CGRID (NTILE*2*BATCH) // 1664 = 8 XCDs * 208

typedef unsigned short u16;
typedef __attribute__((ext_vector_type(8))) short short8_t;   // 8 bf16 = 4 VGPR
typedef __attribute__((ext_vector_type(16))) float floatx16;  // 32x32 MFMA acc

// +4*PLANE zero tails (never written; .bss zero-init) back the invalid-tap
// offsets: any off in [zoff, zoff+3*PLANE*2+16] reads zeros.
__device__ u16   g_xb[(size_t)BATCH*IMG_ + 4*PLANE];  // x bf16 [b][kq][pos][ch16]
__device__ u16   g_h[(size_t)JOBS*IMG_ + 4*PLANE];    // conv1 out [job][kq][pos][ch16]
__device__ u16   g_pw1[NE * PWSZ];            // packed conv1 w (bn1_s folded)
__device__ u16   g_pw2[NE * PWSZ];            // packed conv2 w (bn2_s folded)
__device__ int   g_eid[JOBS];
__device__ float g_wgt[JOBS];
__device__ float g_pool[49 * BATCH * CH];     // GAP partials [tile49][b][ch]

__device__ __forceinline__ u16 f2b(float f) {
    unsigned v; __builtin_memcpy(&v, &f, 4);
    return (u16)((v + 0x7FFFu + ((v >> 16) & 1u)) >> 16);   // RNE
}

// ---------------- fused prep: pack + xconv (independent outputs) ------------
// grid = 2304 (pack) + 3136 (xconv) blocks of 256. No atomics, no fences.
__global__ __launch_bounds__(256) void prep_kernel(
    const float* __restrict__ x,
    const float* __restrict__ w1, const float* __restrict__ s1,
    const float* __restrict__ w2, const float* __restrict__ s2)
{
    int bid = blockIdx.x;
    int tid = threadIdx.x;
    if (bid < 2304) {                       // ---- pack (whole block) ----
        int idx = bid * 256 + tid;          // < 589824
        int conv = idx / 294912;
        int i2 = idx - conv * 294912;
        int e = i2 / PWSZ;   int r = i2 - e * PWSZ;
        int s36 = r >> 10;   int r2 = r & 1023;
        int mt  = r2 >> 9;   int r3 = r2 & 511;
        int h   = r3 >> 8;   int r4 = r3 & 255;
        int m   = r4 >> 3;   int j  = r4 & 7;
        int tap = s36 >> 2;
        int ci  = ((s36 & 3) << 4) | (h << 3) | j;
        int M   = mt*32 + m;
        const float* w  = conv ? w2 : w1;
        const float* sc = conv ? s2 : s1;
        float v = w[((e*64 + M)*64 + ci)*9 + tap] * sc[e*64 + M];
        (conv ? g_pw2 : g_pw1)[i2] = f2b(v);
        return;
    }
    // ---- xconv: x NCHW f32 -> g_xb [kq][pos][ch16] bf16 + GAP partial ----
    __shared__ u16 T[64*66];                // [pos][ch], stride 66
    int xid = bid - 2304;
    int b = xid / 49;
    int tile = xid - b*49;
    int pos0 = tile * 64;
    int pin = tid & 63;
    int c0 = tid >> 6;                      // 0..3
    const float* xb = x + (size_t)b*IMG_ + pos0 + pin;
    #pragma unroll
    for (int i = 0; i < 16; i++) {
        int ch = c0*16 + i;
        T[pin*66 + ch] = f2b(xb[ch*HW_]);   // coalesced 256B f32 read per instr
    }
    __syncthreads();
    u16* ob = g_xb + (size_t)b*IMG_ + (size_t)pos0*16;   // within-plane offset
    #pragma unroll
    for (int i = 0; i < 16; i++) {
        int j = tid + i*256;                // 0..4095
        int kq  = j >> 10;
        int pos = (j >> 4) & 63;
        int c16 = j & 15;
        ob[(size_t)kq*PLANE + pos*16 + c16] = T[pos*66 + kq*16 + c16];
    }
    // GAP partial: threads 0..63 sum their channel over the 64 positions.
    if (tid < 64) {
        float s = 0.f;
        const float* xc = x + (size_t)b*IMG_ + tid*HW_ + pos0;
        #pragma unroll 4
        for (int p = 0; p < 64; p++) s += xc[p];
        g_pool[tile*(BATCH*CH) + b*64 + tid] = s;
    }
}

// ---------------- gate finalize: pool -> logits -> top2 softmax -------------
__global__ __launch_bounds__(64) void gate_fin_kernel(
    const float* __restrict__ gw, const float* __restrict__ gb,
    float* __restrict__ dw_out)
{
    __shared__ float pooled[CH];
    __shared__ float logits[NE];
    int b = blockIdx.x, t = threadIdx.x;
    float s = 0.f;
    #pragma unroll
    for (int i = 0; i < 49; i++) s += g_pool[i*(BATCH*CH) + b*64 + t];
    pooled[t] = s * (1.f/3136.f);
    __syncthreads();
    if (t < NE) {
        float l = gb[t];
        for (int c = 0; c < CH; c++) l += pooled[c] * gw[t*CH + c];
        logits[t] = l;
    }
    __syncthreads();
    if (t == 0) {
        int i1 = 0; float v1 = logits[0];
        for (int e = 1; e < NE; e++) if (logits[e] > v1) { v1 = logits[e]; i1 = e; }
        int i2 = -1; float v2 = -3.4e38f;
        for (int e = 0; e < NE; e++) if (e != i1 && logits[e] > v2) { v2 = logits[e]; i2 = e; }
        float eb = __expf(v2 - v1);
        float wa = 1.f / (1.f + eb), wb = eb / (1.f + eb);
        for (int e = 0; e < NE; e++) dw_out[b*NE + e] = 0.f;
        dw_out[b*NE + i1] = wa;
        dw_out[b*NE + i2] = wb;
        g_eid[2*b] = i1; g_eid[2*b+1] = i2;
        g_wgt[2*b] = wa; g_wgt[2*b+1] = wb;
    }
}

// Single-shot A stage: both experts' mt-slice, 72KB = 4608 16B-units,
// 9 rounds of 512 threads. AL layout: [s36][es][h][m32][j8].
__device__ __forceinline__ void stageA(
    u16* AL, const u16* __restrict__ pw0, const u16* __restrict__ pw1,
    int mt, int tid)
{
    short8_t st[9];
    #pragma unroll
    for (int i = 0; i < 9; i++) {
        int u = i*512 + tid;
        int es = u >= 2304;
        int r = u - (es ? 2304 : 0);
        int s36 = r >> 6;
        int c = r & 63;
        st[i] = *(const short8_t*)((es ? pw1 : pw0) + s36*1024 + mt*512 + c*8);
    }
    #pragma unroll
    for (int i = 0; i < 9; i++) {
        int u = i*512 + tid;
        int es = u >= 2304;
        int r = u - (es ? 2304 : 0);
        int s36 = r >> 6;
        int c = r & 63;
        *(short8_t*)(AL + (s36*2 + es)*512 + c*8) = st[i];
    }
}

// Per-tap offset tables: valid -> p*32 + h*16 bytes within the base image;
// invalid -> zoff (zero tail). kq adds a compile-time plane-stride constant.
__device__ __forceinline__ void mkOffs(
    unsigned* off, int gn, int y, int xc, int h, unsigned zoff)
{
    #pragma unroll
    for (int tap = 0; tap < 9; tap++) {
        int dy = tap/3 - 1, dx = tap - (tap/3)*3 - 1;
        int p = gn + dy*56 + dx;
        bool vld = ((unsigned)(y + dy) < 56u) && ((unsigned)(xc + dx) < 56u);
        off[tap] = vld ? (unsigned)(p*32 + h*16) : zoff;
    }
}
#define LOADB(base, off, kq) (*(const short8_t*)((base) + (off) + (unsigned)((kq)*PLANE*2)))

// ---------------- conv1 + bn1 + relu -> g_h ---------------------------------
// 1D grid 1664, XCD-chunked decode: L = (wg&7)*208 + wg/8; b = L/26,
// tile = (L%26)>>1, mt = L&1 -> (tile,mt) pairs adjacent on one XCD.
__global__ __launch_bounds__(512, 4) void conv1_kernel(const float* __restrict__ b1)
{
    __shared__ u16 AL[36864];           // 72KB, staged once
    int wg = blockIdx.x;
    int L  = (wg & 7) * (CGRID/8) + (wg >> 3);
    int b  = L / 26;
    int r  = L - b*26;
    int tile = r >> 1;
    int mt   = r & 1;
    int e0 = g_eid[2*b], e1 = g_eid[2*b+1];
    int tid = threadIdx.x;
    int lane = tid & 63, w = tid >> 6;  // 8 waves
    int es = w & 1, pg = w >> 1;        // expert slot (2), position group (4)
    int l31 = lane & 31, h = lane >> 5;
    int gn0 = tile*256 + pg*64 + l31;   // frag 0 position (may be >= 3136)
    int gn1 = gn0 + 32;                 // frag 1 position
    int y0 = gn0/56, xc0 = gn0 - y0*56;
    int y1 = gn1/56, xc1 = gn1 - y1*56;
    int e = es ? e1 : e0;
    const char* base = (const char*)(g_xb + (size_t)b*IMG_);
    unsigned zoff = (unsigned)((size_t)(BATCH - b)*IMG_*2);
    const u16* pw0 = g_pw1 + e0*PWSZ;
    const u16* pw1 = g_pw1 + e1*PWSZ;
    int aOff = es*512 + h*256 + l31*8;  // + s*1024

    unsigned off0[9], off1[9];
    mkOffs(off0, gn0, y0, xc0, h, zoff);
    mkOffs(off1, gn1, y1, xc1, h, zoff);

    floatx16 accA = {}, accB = {};      // frag 0 / frag 1 accumulators
    short8_t B0[BD], B1[BD];
    #pragma unroll
    for (int s = 0; s < BD; s++) {      // B prefetch issues FIRST (longest latency)
        B0[s] = LOADB(base, off0[s >> 2], s & 3);
        B1[s] = LOADB(base, off1[s >> 2], s & 3);
    }
    stageA(AL, pw0, pw1, mt, tid);
    __syncthreads();                    // the ONLY barrier

    short8_t Ar[3];                     // A register pipeline, depth 3
    #pragma unroll
    for (int i = 0; i < 3; i++)
        Ar[i] = *(const short8_t*)(AL + i*1024 + aOff);

    #pragma unroll
    for (int s = 0; s < 36; s++) {
        short8_t bb0 = B0[s % BD];      // capture BEFORE refill
        short8_t bb1 = B1[s % BD];
        int sp = s + BD;
        if (sp < 36) {                  // refill: 1 add + saddr load each
            B0[s % BD] = LOADB(base, off0[sp >> 2], sp & 3);
            B1[s % BD] = LOADB(base, off1[sp >> 2], sp & 3);
        }
        short8_t a = Ar[s % 3];
        if (s + 3 < 36)                 // A refill 3 steps ahead (lgkmcnt cover)
            Ar[s % 3] = *(const short8_t*)(AL + (s+3)*1024 + aOff);
        accA = __builtin_amdgcn_mfma_f32_32x32x16_bf16(a, bb0, accA, 0, 0, 0);
        accB = __builtin_amdgcn_mfma_f32_32x32x16_bf16(a, bb1, accB, 0, 0, 0);
    }

    // epilogue -> g_h [kq][pos][ch16]: kq = mt*2 + (rg>>1), c = (rg&1)*8 + h*4
    u16* hb = g_h + (size_t)(2*b + es)*IMG_;
    #pragma unroll
    for (int f = 0; f < 2; f++) {
        int gn = f ? gn1 : gn0;
        if (gn < HW_) {
            #pragma unroll
            for (int rg = 0; rg < 4; rg++) {
                union { u16 u[4]; uint2 v; } t;
                #pragma unroll
                for (int rr = 0; rr < 4; rr++) {
                    int m = rg*8 + h*4 + rr;       // D row = (reg&3)+8*(reg>>2)+4*h
                    float v = (f ? accB : accA)[rg*4 + rr] + b1[e*64 + mt*32 + m];
                    t.u[rr] = f2b(fmaxf(v, 0.f));
                }
                int kq = mt*2 + (rg >> 1);
                *(uint2*)(hb + (size_t)kq*PLANE + (size_t)gn*16 + (rg & 1)*8 + h*4) = t.v;
            }
        }
    }
}

// ---------------- conv2 + bn2 + residual + cross-wave combine ---------------
__global__ __launch_bounds__(512, 4) void conv2_kernel(
    const float* __restrict__ x, const float* __restrict__ b2,
    float* __restrict__ out)
{
    __shared__ u16 AL[36864];           // 72KB; reused as 32KB f32 P after loop
    int wg = blockIdx.x;
    int L  = (wg & 7) * (CGRID/8) + (wg >> 3);
    int b  = L / 26;                    // SAME b->XCD map as conv1 (h L2 reuse)
    int r  = L - b*26;
    int tile = (NTILE-1) - (r >> 1);    // tile-LIFO within b (newest h first)
    int mt   = r & 1;
    int e0 = g_eid[2*b], e1 = g_eid[2*b+1];
    int tid = threadIdx.x;
    int lane = tid & 63, w = tid >> 6;
    int es = w & 1, pg = w >> 1;
    int l31 = lane & 31, h = lane >> 5;
    int gn0 = tile*256 + pg*64 + l31;
    int gn1 = gn0 + 32;
    int y0 = gn0/56, xc0 = gn0 - y0*56;
    int y1 = gn1/56, xc1 = gn1 - y1*56;
    int e = es ? e1 : e0;
    float wgt = g_wgt[2*b + es];
    const char* base = (const char*)(g_h + (size_t)(2*b + es)*IMG_);
    unsigned zoff = (unsigned)((size_t)(JOBS - (2*b + es))*IMG_*2);
    const u16* pw0 = g_pw2 + e0*PWSZ;
    const u16* pw1 = g_pw2 + e1*PWSZ;
    int aOff = es*512 + h*256 + l31*8;

    unsigned off0[9], off1[9];
    mkOffs(off0, gn0, y0, xc0, h, zoff);
    mkOffs(off1, gn1, y1, xc1, h, zoff);

    floatx16 accA = {}, accB = {};
    short8_t B0[BD], B1[BD];
    #pragma unroll
    for (int s = 0; s < BD; s++) {
        B0[s] = LOADB(base, off0[s >> 2], s & 3);
        B1[s] = LOADB(base, off1[s >> 2], s & 3);
    }
    stageA(AL, pw0, pw1, mt, tid);
    __syncthreads();

    short8_t Ar[3];
    #pragma unroll
    for (int i = 0; i < 3; i++)
        Ar[i] = *(const short8_t*)(AL + i*1024 + aOff);

    #pragma unroll
    for (int s = 0; s < 36; s++) {
        short8_t bb0 = B0[s % BD];      // capture BEFORE refill
        short8_t bb1 = B1[s % BD];
        int sp = s + BD;
        if (sp < 36) {
            B0[s % BD] = LOADB(base, off0[sp >> 2], sp & 3);
            B1[s % BD] = LOADB(base, off1[sp >> 2], sp & 3);
        }
        short8_t a = Ar[s % 3];
        if (s + 3 < 36)
            Ar[s % 3] = *(const short8_t*)(AL + (s+3)*1024 + aOff);
        accA = __builtin_amdgcn_mfma_f32_32x32x16_bf16(a, bb0, accA, 0, 0, 0);
        accB = __builtin_amdgcn_mfma_f32_32x32x16_bf16(a, bb1, accB, 0, 0, 0);
    }

    // combine: es0 waves drop w0*relu(y0+x) into LDS, es1 waves add+store.
    __syncthreads();                    // all waves done reading AL
    float* P = (float*)AL;              // [pg][f][m32][l31] f32 = 32KB
    const float* xb = x + (size_t)b*IMG_ + (size_t)(mt*32)*HW_;
    if (es == 0) {
        #pragma unroll
        for (int f = 0; f < 2; f++) {
            int gn = f ? gn1 : gn0;
            if (gn < HW_) {
                #pragma unroll
                for (int rg = 0; rg < 4; rg++)
                    #pragma unroll
                    for (int rr = 0; rr < 4; rr++) {
                        int m = rg*8 + h*4 + rr;
                        float v = (f ? accB : accA)[rg*4 + rr] + b2[e*64 + mt*32 + m]
                                  + xb[(size_t)m*HW_ + gn];
                        P[((pg*2 + f)*32 + m)*32 + l31] = wgt * fmaxf(v, 0.f);
                    }
            }
        }
    }
    __syncthreads();
    if (es == 1) {
        float* ob = out + (size_t)b*IMG_ + (size_t)(mt*32)*HW_;
        #pragma unroll
        for (int f = 0; f < 2; f++) {
            int gn = f ? gn1 : gn0;
            if (gn < HW_) {
                #pragma unroll
                for (int rg = 0; rg < 4; rg++)
                    #pragma unroll
                    for (int rr = 0; rr < 4; rr++) {
                        int m = rg*8 + h*4 + rr;
                        float v = (f ? accB : accA)[rg*4 + rr] + b2[e*64 + mt*32 + m]
                                  + xb[(size_t)m*HW_ + gn];
                        ob[(size_t)m*HW_ + gn] = wgt * fmaxf(v, 0.f)
                                                 + P[((pg*2 + f)*32 + m)*32 + l31];
                    }
            }
        }
    }
}

extern "C" void kernel_launch(void* const* d_in, const int* in_sizes, int n_in,
                              void* d_out, int out_size, void* d_ws, size_t ws_size,
                              hipStream_t stream) {
    const float* x   = (const float*)d_in[0];
    const float* gw  = (const float*)d_in[1];
    const float* gb  = (const float*)d_in[2];
    const float* w1  = (const float*)d_in[3];
    const float* s1  = (const float*)d_in[4];
    const float* b1  = (const float*)d_in[5];
    const float* w2  = (const float*)d_in[6];
    const float* s2  = (const float*)d_in[7];
    const float* b2  = (const float*)d_in[8];
    float* out = (float*)d_out;
    float* dw  = out + (size_t)BATCH * IMG_;   // dense_w region of d_out (f32)

    (void)d_ws; (void)ws_size;                 // zero d_ws usage (R1/R2 aborts)

    hipLaunchKernelGGL(prep_kernel, dim3(2304 + 3136), dim3(256), 0, stream,
                       x, w1, s1, w2, s2);
    hipLaunchKernelGGL(gate_fin_kernel, dim3(BATCH), dim3(64), 0, stream, gw, gb, dw);
    hipLaunchKernelGGL(conv1_kernel, dim3(CGRID), dim3(512), 0, stream, b1);
    hipLaunchKernelGGL(conv2_kernel, dim3(CGRID), dim3(512), 0, stream, x, b2, out);
}

// Round 10
// 236.169 us; speedup vs baseline: 2.3118x; 1.0309x over previous
//
#include <hip/hip_runtime.h>

// ResNetBlock_MoE: B=64,C=64,H=W=56,E=8,TOPK=2. f32 in / f32 out.
// out = sum_k w_k*relu(bn2(conv2(relu(bn1(conv1(x,e)))))+x), plus dense_w.
//
// R21: R20 post-mortem — VGPR=64 proves the depth-6 B pipeline collapsed:
// hipcc's scheduler sank refill loads to their uses (min-pressure), so B
// latency (~200-300cy L2) is uncovered each step; MfmaUtil 18% vs 12.5us
// MFMA floor. Fixes:
//  1. sched_group_barrier per unrolled step: pin {2 VMEM_READ, 1 DS_READ,
//     2 MFMA} -> loads for step s+6 must be EMITTED before step-s MFMAs,
//     forcing regalloc to hold ~12 loads in flight (real depth-6 pipeline).
//  2. kq plane bases as 4 uniform SGPR pointers (bk[kq]) -> refill is a bare
//     global_load_dwordx4 v,voff,s[bk] with zero per-load VALU.
// Keeps: zero-page offset tables, kq-plane activations, barrier-free 36-step
// loop, conflict-free A LDS, XCD-chunked swizzle, A-reg pipeline depth 3,
// B depth 6, conv2 LDS combine, capture-before-refill, 4-launch structure.

#define BATCH 64
#define CH    64
#define HW_   3136            // 56*56
#define IMG_  (CH*HW_)        // 200704
#define PLANE (HW_*16)        // 50176 u16: one kq-plane [pos][ch16]
#define NE    8
#define JOBS  128
#define PWSZ  36864           // per-expert packed weights: 36*2mt*2h*32m*8j (u16)
#define NTILE 13              // ceil(3136/256) position tiles
#define BD    6               // B-prefetch depth in steps (x2 frags = 12 loads)
#define CGRID (NTILE*2*BATCH) // 1664 = 8 XCDs * 208

typedef unsigned short u16;
typedef __attribute__((ext_vector_type(8))) short short8_t;   // 8 bf16 = 4 VGPR
typedef __attribute__((ext_vector_type(16))) float floatx16;  // 32x32 MFMA acc

// +4*PLANE zero tails (never written; .bss zero-init) back the invalid-tap
// offsets: any off in [zoff, zoff+3*PLANE*2+16] reads zeros.
__device__ u16   g_xb[(size_t)BATCH*IMG_ + 4*PLANE];  // x bf16 [b][kq][pos][ch16]
__device__ u16   g_h[(size_t)JOBS*IMG_ + 4*PLANE];    // conv1 out [job][kq][pos][ch16]
__device__ u16   g_pw1[NE * PWSZ];            // packed conv1 w (bn1_s folded)
__device__ u16   g_pw2[NE * PWSZ];            // packed conv2 w (bn2_s folded)
__device__ int   g_eid[JOBS];
__device__ float g_wgt[JOBS];
__device__ float g_pool[49 * BATCH * CH];     // GAP partials [tile49][b][ch]

__device__ __forceinline__ u16 f2b(float f) {
    unsigned v; __builtin_memcpy(&v, &f, 4);
    return (u16)((v + 0x7FFFu + ((v >> 16) & 1u)) >> 16);   // RNE
}

// ---------------- fused prep: pack + xconv (independent outputs) ------------
// grid = 2304 (pack) + 3136 (xconv) blocks of 256. No atomics, no fences.
__global__ __launch_bounds__(256) void prep_kernel(
    const float* __restrict__ x,
    const float* __restrict__ w1, const float* __restrict__ s1,
    const float* __restrict__ w2, const float* __restrict__ s2)
{
    int bid = blockIdx.x;
    int tid = threadIdx.x;
    if (bid < 2304) {                       // ---- pack (whole block) ----
        int idx = bid * 256 + tid;          // < 589824
        int conv = idx / 294912;
        int i2 = idx - conv * 294912;
        int e = i2 / PWSZ;   int r = i2 - e * PWSZ;
        int s36 = r >> 10;   int r2 = r & 1023;
        int mt  = r2 >> 9;   int r3 = r2 & 511;
        int h   = r3 >> 8;   int r4 = r3 & 255;
        int m   = r4 >> 3;   int j  = r4 & 7;
        int tap = s36 >> 2;
        int ci  = ((s36 & 3) << 4) | (h << 3) | j;
        int M   = mt*32 + m;
        const float* w  = conv ? w2 : w1;
        const float* sc = conv ? s2 : s1;
        float v = w[((e*64 + M)*64 + ci)*9 + tap] * sc[e*64 + M];
        (conv ? g_pw2 : g_pw1)[i2] = f2b(v);
        return;
    }
    // ---- xconv: x NCHW f32 -> g_xb [kq][pos][ch16] bf16 + GAP partial ----
    __shared__ u16 T[64*66];                // [pos][ch], stride 66
    int xid = bid - 2304;
    int b = xid / 49;
    int tile = xid - b*49;
    int pos0 = tile * 64;
    int pin = tid & 63;
    int c0 = tid >> 6;                      // 0..3
    const float* xb = x + (size_t)b*IMG_ + pos0 + pin;
    #pragma unroll
    for (int i = 0; i < 16; i++) {
        int ch = c0*16 + i;
        T[pin*66 + ch] = f2b(xb[ch*HW_]);   // coalesced 256B f32 read per instr
    }
    __syncthreads();
    u16* ob = g_xb + (size_t)b*IMG_ + (size_t)pos0*16;   // within-plane offset
    #pragma unroll
    for (int i = 0; i < 16; i++) {
        int j = tid + i*256;                // 0..4095
        int kq  = j >> 10;
        int pos = (j >> 4) & 63;
        int c16 = j & 15;
        ob[(size_t)kq*PLANE + pos*16 + c16] = T[pos*66 + kq*16 + c16];
    }
    // GAP partial: threads 0..63 sum their channel over the 64 positions.
    if (tid < 64) {
        float s = 0.f;
        const float* xc = x + (size_t)b*IMG_ + tid*HW_ + pos0;
        #pragma unroll 4
        for (int p = 0; p < 64; p++) s += xc[p];
        g_pool[tile*(BATCH*CH) + b*64 + tid] = s;
    }
}

// ---------------- gate finalize: pool -> logits -> top2 softmax -------------
__global__ __launch_bounds__(64) void gate_fin_kernel(
    const float* __restrict__ gw, const float* __restrict__ gb,
    float* __restrict__ dw_out)
{
    __shared__ float pooled[CH];
    __shared__ float logits[NE];
    int b = blockIdx.x, t = threadIdx.x;
    float s = 0.f;
    #pragma unroll
    for (int i = 0; i < 49; i++) s += g_pool[i*(BATCH*CH) + b*64 + t];
    pooled[t] = s * (1.f/3136.f);
    __syncthreads();
    if (t < NE) {
        float l = gb[t];
        for (int c = 0; c < CH; c++) l += pooled[c] * gw[t*CH + c];
        logits[t] = l;
    }
    __syncthreads();
    if (t == 0) {
        int i1 = 0; float v1 = logits[0];
        for (int e = 1; e < NE; e++) if (logits[e] > v1) { v1 = logits[e]; i1 = e; }
        int i2 = -1; float v2 = -3.4e38f;
        for (int e = 0; e < NE; e++) if (e != i1 && logits[e] > v2) { v2 = logits[e]; i2 = e; }
        float eb = __expf(v2 - v1);
        float wa = 1.f / (1.f + eb), wb = eb / (1.f + eb);
        for (int e = 0; e < NE; e++) dw_out[b*NE + e] = 0.f;
        dw_out[b*NE + i1] = wa;
        dw_out[b*NE + i2] = wb;
        g_eid[2*b] = i1; g_eid[2*b+1] = i2;
        g_wgt[2*b] = wa; g_wgt[2*b+1] = wb;
    }
}

// Single-shot A stage: both experts' mt-slice, 72KB = 4608 16B-units,
// 9 rounds of 512 threads. AL layout: [s36][es][h][m32][j8].
__device__ __forceinline__ void stageA(
    u16* AL, const u16* __restrict__ pw0, const u16* __restrict__ pw1,
    int mt, int tid)
{
    short8_t st[9];
    #pragma unroll
    for (int i = 0; i < 9; i++) {
        int u = i*512 + tid;
        int es = u >= 2304;
        int r = u - (es ? 2304 : 0);
        int s36 = r >> 6;
        int c = r & 63;
        st[i] = *(const short8_t*)((es ? pw1 : pw0) + s36*1024 + mt*512 + c*8);
    }
    #pragma unroll
    for (int i = 0; i < 9; i++) {
        int u = i*512 + tid;
        int es = u >= 2304;
        int r = u - (es ? 2304 : 0);
        int s36 = r >> 6;
        int c = r & 63;
        *(short8_t*)(AL + (s36*2 + es)*512 + c*8) = st[i];
    }
}

// Per-tap offset tables: valid -> p*32 + h*16 bytes within the kq-plane;
// invalid -> zoff (zero tail past the image array).
__device__ __forceinline__ void mkOffs(
    unsigned* off, int gn, int y, int xc, int h, unsigned zoff)
{
    #pragma unroll
    for (int tap = 0; tap < 9; tap++) {
        int dy = tap/3 - 1, dx = tap - (tap/3)*3 - 1;
        int p = gn + dy*56 + dx;
        bool vld = ((unsigned)(y + dy) < 56u) && ((unsigned)(xc + dx) < 56u);
        off[tap] = vld ? (unsigned)(p*32 + h*16) : zoff;
    }
}
#define LOADB(bk, off) (*(const short8_t*)((bk) + (off)))

// Per-step schedule pin: emit {2 VMEM_READ (B refills s+6), 1 DS_READ (A
// refill s+3), 2 MFMA (step s)} -> forces the depth-6 pipeline into regalloc.
// Masks: VMEM_READ=0x20, DS_READ=0x100, MFMA=0x8.
#define STEP_SGB(HAS_VMEM, HAS_DS)                                   \
    do {                                                             \
        if (HAS_VMEM) __builtin_amdgcn_sched_group_barrier(0x020, 2, 0); \
        if (HAS_DS)   __builtin_amdgcn_sched_group_barrier(0x100, 1, 0); \
        __builtin_amdgcn_sched_group_barrier(0x008, 2, 0);           \
    } while (0)

// ---------------- conv1 + bn1 + relu -> g_h ---------------------------------
// 1D grid 1664, XCD-chunked decode: L = (wg&7)*208 + wg/8; b = L/26,
// tile = (L%26)>>1, mt = L&1 -> (tile,mt) pairs adjacent on one XCD.
__global__ __launch_bounds__(512, 4) void conv1_kernel(const float* __restrict__ b1)
{
    __shared__ u16 AL[36864];           // 72KB, staged once
    int wg = blockIdx.x;
    int L  = (wg & 7) * (CGRID/8) + (wg >> 3);
    int b  = L / 26;
    int r  = L - b*26;
    int tile = r >> 1;
    int mt   = r & 1;
    int e0 = g_eid[2*b], e1 = g_eid[2*b+1];
    int tid = threadIdx.x;
    int lane = tid & 63, w = tid >> 6;  // 8 waves
    int es = w & 1, pg = w >> 1;        // expert slot (2), position group (4)
    int l31 = lane & 31, h = lane >> 5;
    int gn0 = tile*256 + pg*64 + l31;   // frag 0 position (may be >= 3136)
    int gn1 = gn0 + 32;                 // frag 1 position
    int y0 = gn0/56, xc0 = gn0 - y0*56;
    int y1 = gn1/56, xc1 = gn1 - y1*56;
    int e = es ? e1 : e0;
    const char* base = (const char*)(g_xb + (size_t)b*IMG_);
    const char* bk0 = base;                      // uniform SGPR plane bases
    const char* bk1 = base + PLANE*2;
    const char* bk2 = base + 2*PLANE*2;
    const char* bk3 = base + 3*PLANE*2;
    unsigned zoff = (unsigned)((size_t)(BATCH - b)*IMG_*2);
    const u16* pw0 = g_pw1 + e0*PWSZ;
    const u16* pw1 = g_pw1 + e1*PWSZ;
    int aOff = es*512 + h*256 + l31*8;  // + s*1024

    unsigned off0[9], off1[9];
    mkOffs(off0, gn0, y0, xc0, h, zoff);
    mkOffs(off1, gn1, y1, xc1, h, zoff);

    floatx16 accA = {}, accB = {};      // frag 0 / frag 1 accumulators
    short8_t B0[BD], B1[BD];
    #pragma unroll
    for (int s = 0; s < BD; s++) {      // B prefetch issues FIRST (longest latency)
        const char* bk = (s&3)==0 ? bk0 : (s&3)==1 ? bk1 : (s&3)==2 ? bk2 : bk3;
        B0[s] = LOADB(bk, off0[s >> 2]);
        B1[s] = LOADB(bk, off1[s >> 2]);
    }
    stageA(AL, pw0, pw1, mt, tid);
    __syncthreads();                    // the ONLY barrier

    short8_t Ar[3];                     // A register pipeline, depth 3
    #pragma unroll
    for (int i = 0; i < 3; i++)
        Ar[i] = *(const short8_t*)(AL + i*1024 + aOff);

    #pragma unroll
    for (int s = 0; s < 36; s++) {
        short8_t bb0 = B0[s % BD];      // capture BEFORE refill
        short8_t bb1 = B1[s % BD];
        int sp = s + BD;
        if (sp < 36) {                  // refill: bare saddr+voffset loads
            const char* bk = (sp&3)==0 ? bk0 : (sp&3)==1 ? bk1 : (sp&3)==2 ? bk2 : bk3;
            B0[s % BD] = LOADB(bk, off0[sp >> 2]);
            B1[s % BD] = LOADB(bk, off1[sp >> 2]);
        }
        short8_t a = Ar[s % 3];
        if (s + 3 < 36)                 // A refill 3 steps ahead (lgkmcnt cover)
            Ar[s % 3] = *(const short8_t*)(AL + (s+3)*1024 + aOff);
        accA = __builtin_amdgcn_mfma_f32_32x32x16_bf16(a, bb0, accA, 0, 0, 0);
        accB = __builtin_amdgcn_mfma_f32_32x32x16_bf16(a, bb1, accB, 0, 0, 0);
        STEP_SGB(sp < 36, s + 3 < 36);
    }

    // epilogue -> g_h [kq][pos][ch16]: kq = mt*2 + (rg>>1), c = (rg&1)*8 + h*4
    u16* hb = g_h + (size_t)(2*b + es)*IMG_;
    #pragma unroll
    for (int f = 0; f < 2; f++) {
        int gn = f ? gn1 : gn0;
        if (gn < HW_) {
            #pragma unroll
            for (int rg = 0; rg < 4; rg++) {
                union { u16 u[4]; uint2 v; } t;
                #pragma unroll
                for (int rr = 0; rr < 4; rr++) {
                    int m = rg*8 + h*4 + rr;       // D row = (reg&3)+8*(reg>>2)+4*h
                    float v = (f ? accB : accA)[rg*4 + rr] + b1[e*64 + mt*32 + m];
                    t.u[rr] = f2b(fmaxf(v, 0.f));
                }
                int kq = mt*2 + (rg >> 1);
                *(uint2*)(hb + (size_t)kq*PLANE + (size_t)gn*16 + (rg & 1)*8 + h*4) = t.v;
            }
        }
    }
}

// ---------------- conv2 + bn2 + residual + cross-wave combine ---------------
__global__ __launch_bounds__(512, 4) void conv2_kernel(
    const float* __restrict__ x, const float* __restrict__ b2,
    float* __restrict__ out)
{
    __shared__ u16 AL[36864];           // 72KB; reused as 32KB f32 P after loop
    int wg = blockIdx.x;
    int L  = (wg & 7) * (CGRID/8) + (wg >> 3);
    int b  = L / 26;                    // SAME b->XCD map as conv1 (h L2 reuse)
    int r  = L - b*26;
    int tile = (NTILE-1) - (r >> 1);    // tile-LIFO within b (newest h first)
    int mt   = r & 1;
    int e0 = g_eid[2*b], e1 = g_eid[2*b+1];
    int tid = threadIdx.x;
    int lane = tid & 63, w = tid >> 6;
    int es = w & 1, pg = w >> 1;
    int l31 = lane & 31, h = lane >> 5;
    int gn0 = tile*256 + pg*64 + l31;
    int gn1 = gn0 + 32;
    int y0 = gn0/56, xc0 = gn0 - y0*56;
    int y1 = gn1/56, xc1 = gn1 - y1*56;
    int e = es ? e1 : e0;
    float wgt = g_wgt[2*b + es];
    const char* base = (const char*)(g_h + (size_t)(2*b + es)*IMG_);
    const char* bk0 = base;
    const char* bk1 = base + PLANE*2;
    const char* bk2 = base + 2*PLANE*2;
    const char* bk3 = base + 3*PLANE*2;
    unsigned zoff = (unsigned)((size_t)(JOBS - (2*b + es))*IMG_*2);
    const u16* pw0 = g_pw2 + e0*PWSZ;
    const u16* pw1 = g_pw2 + e1*PWSZ;
    int aOff = es*512 + h*256 + l31*8;

    unsigned off0[9], off1[9];
    mkOffs(off0, gn0, y0, xc0, h, zoff);
    mkOffs(off1, gn1, y1, xc1, h, zoff);

    floatx16 accA = {}, accB = {};
    short8_t B0[BD], B1[BD];
    #pragma unroll
    for (int s = 0; s < BD; s++) {
        const char* bk = (s&3)==0 ? bk0 : (s&3)==1 ? bk1 : (s&3)==2 ? bk2 : bk3;
        B0[s] = LOADB(bk, off0[s >> 2]);
        B1[s] = LOADB(bk, off1[s >> 2]);
    }
    stageA(AL, pw0, pw1, mt, tid);
    __syncthreads();

    short8_t Ar[3];
    #pragma unroll
    for (int i = 0; i < 3; i++)
        Ar[i] = *(const short8_t*)(AL + i*1024 + aOff);

    #pragma unroll
    for (int s = 0; s < 36; s++) {
        short8_t bb0 = B0[s % BD];      // capture BEFORE refill
        short8_t bb1 = B1[s % BD];
        int sp = s + BD;
        if (sp < 36) {
            const char* bk = (sp&3)==0 ? bk0 : (sp&3)==1 ? bk1 : (sp&3)==2 ? bk2 : bk3;
            B0[s % BD] = LOADB(bk, off0[sp >> 2]);
            B1[s % BD] = LOADB(bk, off1[sp >> 2]);
        }
        short8_t a = Ar[s % 3];
        if (s + 3 < 36)
            Ar[s % 3] = *(const short8_t*)(AL + (s+3)*1024 + aOff);
        accA = __builtin_amdgcn_mfma_f32_32x32x16_bf16(a, bb0, accA, 0, 0, 0);
        accB = __builtin_amdgcn_mfma_f32_32x32x16_bf16(a, bb1, accB, 0, 0, 0);
        STEP_SGB(sp < 36, s + 3 < 36);
    }

    // combine: es0 waves drop w0*relu(y0+x) into LDS, es1 waves add+store.
    __syncthreads();                    // all waves done reading AL
    float* P = (float*)AL;              // [pg][f][m32][l31] f32 = 32KB
    const float* xb = x + (size_t)b*IMG_ + (size_t)(mt*32)*HW_;
    if (es == 0) {
        #pragma unroll
        for (int f = 0; f < 2; f++) {
            int gn = f ? gn1 : gn0;
            if (gn < HW_) {
                #pragma unroll
                for (int rg = 0; rg < 4; rg++)
                    #pragma unroll
                    for (int rr = 0; rr < 4; rr++) {
                        int m = rg*8 + h*4 + rr;
                        float v = (f ? accB : accA)[rg*4 + rr] + b2[e*64 + mt*32 + m]
                                  + xb[(size_t)m*HW_ + gn];
                        P[((pg*2 + f)*32 + m)*32 + l31] = wgt * fmaxf(v, 0.f);
                    }
            }
        }
    }
    __syncthreads();
    if (es == 1) {
        float* ob = out + (size_t)b*IMG_ + (size_t)(mt*32)*HW_;
        #pragma unroll
        for (int f = 0; f < 2; f++) {
            int gn = f ? gn1 : gn0;
            if (gn < HW_) {
                #pragma unroll
                for (int rg = 0; rg < 4; rg++)
                    #pragma unroll
                    for (int rr = 0; rr < 4; rr++) {
                        int m = rg*8 + h*4 + rr;
                        float v = (f ? accB : accA)[rg*4 + rr] + b2[e*64 + mt*32 + m]
                                  + xb[(size_t)m*HW_ + gn];
                        ob[(size_t)m*HW_ + gn] = wgt * fmaxf(v, 0.f)
                                                 + P[((pg*2 + f)*32 + m)*32 + l31];
                    }
            }
        }
    }
}

extern "C" void kernel_launch(void* const* d_in, const int* in_sizes, int n_in,
                              void* d_out, int out_size, void* d_ws, size_t ws_size,
                              hipStream_t stream) {
    const float* x   = (const float*)d_in[0];
    const float* gw  = (const float*)d_in[1];
    const float* gb  = (const float*)d_in[2];
    const float* w1  = (const float*)d_in[3];
    const float* s1  = (const float*)d_in[4];
    const float* b1  = (const float*)d_in[5];
    const float* w2  = (const float*)d_in[6];
    const float* s2  = (const float*)d_in[7];
    const float* b2  = (const float*)d_in[8];
    float* out = (float*)d_out;
    float* dw  = out + (size_t)BATCH * IMG_;   // dense_w region of d_out (f32)

    (void)d_ws; (void)ws_size;                 // zero d_ws usage (R1/R2 aborts)

    hipLaunchKernelGGL(prep_kernel, dim3(2304 + 3136), dim3(256), 0, stream,
                       x, w1, s1, w2, s2);
    hipLaunchKernelGGL(gate_fin_kernel, dim3(BATCH), dim3(64), 0, stream, gw, gb, dw);
    hipLaunchKernelGGL(conv1_kernel, dim3(CGRID), dim3(512), 0, stream, b1);
    hipLaunchKernelGGL(conv2_kernel, dim3(CGRID), dim3(512), 0, stream, x, b2, out);
}